// Round 11
// baseline (181.797 us; speedup 1.0000x reference)
//
#include <hip/hip_runtime.h>
#include <math.h>

#define F4(p)  (*reinterpret_cast<float4*>(p))
#define CF4(p) (*reinterpret_cast<const float4*>(p))

#define ROWS  32      // fixed l-rows per k_fa block
#define MAXC  32      // max chunks per batch

// ============ shared 64x64-tile GEMM core (256 threads) ============
__device__ __forceinline__ void gemm_core(
    const float* __restrict__ Asrc, const float* __restrict__ inbias,
    const float* __restrict__ til,
    int NS, int srcld, int kc, int k0,
    const float* __restrict__ W, int ldw, int n0,
    const float* __restrict__ obias, float* __restrict__ Pout, int ldo)
{
    __shared__ float As[16*64], Ws[16*64];
    const int t = threadIdx.x;
    const int tx = t & 15, ty = t >> 4;
    const int row = t >> 2, kq = (t & 3) * 4;
    const int wrow = t >> 4, wcol = (t & 15) * 4;
    float acc[4][4] = {};
    for (int kk = 0; kk < kc; kk += 16) {
        const int kg = k0 + kk + kq;
        float4 av;
        if (til && kg >= 256) {
            av = CF4(&til[row*256 + (kg - 256)]);
        } else {
            av = {0.f, 0.f, 0.f, 0.f};
            if (inbias) av = CF4(&inbias[kg]);
            for (int s = 0; s < NS; ++s) {
                float4 v = CF4(&Asrc[(size_t)(s*64 + row)*srcld + kg]);
                av.x += v.x; av.y += v.y; av.z += v.z; av.w += v.w;
            }
        }
        As[(kq+0)*64+row] = av.x; As[(kq+1)*64+row] = av.y;
        As[(kq+2)*64+row] = av.z; As[(kq+3)*64+row] = av.w;
        F4(&Ws[wrow*64 + wcol]) = CF4(&W[(size_t)(k0 + kk + wrow)*ldw + n0 + wcol]);
        __syncthreads();
        #pragma unroll
        for (int k = 0; k < 16; ++k) {
            float4 a4 = CF4(&As[k*64 + ty*4]);
            float4 w4 = CF4(&Ws[k*64 + tx*4]);
            float a[4] = {a4.x, a4.y, a4.z, a4.w};
            float w[4] = {w4.x, w4.y, w4.z, w4.w};
            #pragma unroll
            for (int i = 0; i < 4; ++i)
                #pragma unroll
                for (int j = 0; j < 4; ++j)
                    acc[i][j] += a[i] * w[j];
        }
        __syncthreads();
    }
    #pragma unroll
    for (int i = 0; i < 4; ++i) {
        float4 o = {acc[i][0], acc[i][1], acc[i][2], acc[i][3]};
        if (obias) {
            float4 ob = CF4(&obias[n0 + tx*4]);
            o.x += ob.x; o.y += ob.y; o.z += ob.z; o.w += ob.w;
        }
        F4(&Pout[(size_t)(ty*4 + i)*ldo + n0 + tx*4]) = o;
    }
}

// ============ q-chain as split-K GEMMs ============
__global__ __launch_bounds__(256) void k_q1(
    const float* __restrict__ state, const float* __restrict__ W_state,
    float* __restrict__ P1)
{
    const int nt = blockIdx.x, ks = blockIdx.y;     // 4 x 8
    gemm_core(state, nullptr, nullptr, 1, 512, 64, ks*64,
              W_state, 256, nt*64, nullptr, P1 + (size_t)ks*64*256, 256);
}

__global__ __launch_bounds__(256) void k_q2(
    const float* __restrict__ P1, const float* __restrict__ b_state,
    const float* __restrict__ til, const float* __restrict__ Wcq1,
    float* __restrict__ P2)
{
    const int nt = blockIdx.x, ks = blockIdx.y;     // 8 x 8
    gemm_core(P1, b_state, til, 8, 256, 64, ks*64,
              Wcq1, 512, nt*64, nullptr, P2 + (size_t)ks*64*512, 512);
}

__global__ __launch_bounds__(256) void k_q3(
    const float* __restrict__ P2, const float* __restrict__ bcq1,
    const float* __restrict__ Wcq2, float* __restrict__ P3)
{
    const int nt = blockIdx.x, ks = blockIdx.y;     // 8 x 8
    gemm_core(P2, bcq1, nullptr, 8, 512, 64, ks*64,
              Wcq2, 512, nt*64, nullptr, P3 + (size_t)ks*64*512, 512);
}

__global__ __launch_bounds__(256) void k_qh(
    const float* __restrict__ P3, const float* __restrict__ bcq2,
    const float* __restrict__ Wq, float* __restrict__ P4)
{
    const int nt = blockIdx.x, ks = blockIdx.y;     // 64 x 4
    gemm_core(P3, bcq2, nullptr, 8, 512, 128, ks*128,
              Wq, 4096, nt*64, nullptr, P4 + (size_t)ks*64*4096, 4096);
}

// ============ k_qsum: qh[b] = bq + sum4 P4 ============
__global__ __launch_bounds__(256) void k_qsum(
    const float* __restrict__ P4, const float* __restrict__ bq,
    float* __restrict__ qh)
{
    const int b = blockIdx.x, t = threadIdx.x;
    #pragma unroll
    for (int j = 0; j < 4; ++j) {
        int f = t + j*256;
        float4 v = CF4(&bq[f*4]);
        #pragma unroll
        for (int s = 0; s < 4; ++s) {
            float4 u = CF4(&P4[(size_t)(s*64 + b)*4096 + f*4]);
            v.x += u.x; v.y += u.y; v.z += u.z; v.w += u.w;
        }
        F4(&qh[(size_t)b*4096 + f*4]) = v;
    }
}

// ============ k_fa: flash attention, uniform 32-row chunks ============
__global__ __launch_bounds__(256, 4) void k_fa(
    const float* __restrict__ keys, const float* __restrict__ rpe,
    const float* __restrict__ qh, const float* __restrict__ vals,
    const int* __restrict__ step,
    float* __restrict__ Facc, float* __restrict__ Fms)
{
    __shared__ float s_q[4096];
    __shared__ float s_sc[ROWS*8];
    __shared__ float red[256];
    __shared__ float s_m[8];
    const int b = blockIdx.y, lc = blockIdx.x;
    const int sb = step[b];
    const int l0 = lc * ROWS;
    if (l0 >= sb) return;                 // dead chunk: no writes at all
    const int nl = min(ROWS, sb - l0);
    const int t = threadIdx.x;
    float* facc_out = Facc + ((size_t)(lc*64) + b)*4096;

    for (int i = t; i < 1024; i += 256)
        F4(&s_q[i*4]) = CF4(&qh[(size_t)b*4096 + i*4]);
    __syncthreads();
    const int lane = t & 63, w = t >> 6;
    float qr[8][8];
    #pragma unroll
    for (int h = 0; h < 8; ++h) {
        float4 x = CF4(&s_q[h*512 + lane*8]);
        float4 y = CF4(&s_q[h*512 + lane*8 + 4]);
        qr[h][0]=x.x; qr[h][1]=x.y; qr[h][2]=x.z; qr[h][3]=x.w;
        qr[h][4]=y.x; qr[h][5]=y.y; qr[h][6]=y.z; qr[h][7]=y.w;
    }
    const float inv_sqrtK = 0.04419417382415922f;
    const bool p0 = lane & 1, p1 = lane & 2, p2 = lane & 4;
    // --- scores, depth-2 prefetch ring ---
    const size_t kstride = (size_t)4*64*512;
    const float* kp = keys + ((size_t)(l0 + w)*64 + b)*512 + lane*8;
    float4 k0x, k0y, k1x, k1y;
    if (w < nl)     { k0x = CF4(kp);           k0y = CF4(kp + 4); }
    if (w + 4 < nl) { k1x = CF4(kp + kstride); k1y = CF4(kp + kstride + 4); }
    for (int il = w; il < nl; il += 4) {
        float kv[8] = {k0x.x,k0x.y,k0x.z,k0x.w, k0y.x,k0y.y,k0y.z,k0y.w};
        k0x = k1x; k0y = k1y;
        if (il + 8 < nl) { k1x = CF4(kp + 2*kstride); k1y = CF4(kp + 2*kstride + 4); }
        kp += kstride;
        float pr[8] = {};
        #pragma unroll
        for (int h = 0; h < 8; ++h)
            #pragma unroll
            for (int j = 0; j < 8; ++j)
                pr[h] += kv[j] * qr[h][j];
        float w4[4], x2[2], y;
        #pragma unroll
        for (int i = 0; i < 4; ++i) {
            float keep = p0 ? pr[2*i+1] : pr[2*i];
            float send = p0 ? pr[2*i]   : pr[2*i+1];
            w4[i] = keep + __shfl_xor(send, 1);
        }
        #pragma unroll
        for (int i = 0; i < 2; ++i) {
            float keep = p1 ? w4[2*i+1] : w4[2*i];
            float send = p1 ? w4[2*i]   : w4[2*i+1];
            x2[i] = keep + __shfl_xor(send, 2);
        }
        {
            float keep = p2 ? x2[1] : x2[0];
            float send = p2 ? x2[0] : x2[1];
            y = keep + __shfl_xor(send, 4);
        }
        y += __shfl_xor(y, 8);
        y += __shfl_xor(y, 16);
        y += __shfl_xor(y, 32);
        if (lane < 8)
            s_sc[il*8 + lane] = y * rpe[(l0 + il)*64 + b] * inv_sqrtK;
    }
    __syncthreads();
    // --- local softmax stats (nl <= 32) ---
    const int h = t & 7, g = t >> 3;
    float m = -1e30f;
    for (int l = g; l < nl; l += 32) m = fmaxf(m, s_sc[l*8 + h]);
    red[g*8 + h] = m;
    __syncthreads();
    #pragma unroll
    for (int s = 16; s; s >>= 1) {
        if (g < s) red[g*8+h] = fmaxf(red[g*8+h], red[(g+s)*8+h]);
        __syncthreads();
    }
    if (t < 8) s_m[t] = red[t];
    __syncthreads();
    float mh = s_m[h], s_acc = 0.f;
    for (int l = g; l < nl; l += 32) {
        float e = __expf(s_sc[l*8 + h] - mh);
        s_sc[l*8 + h] = e;
        s_acc += e;
    }
    red[g*8 + h] = s_acc;
    __syncthreads();
    #pragma unroll
    for (int s = 16; s; s >>= 1) {
        if (g < s) red[g*8+h] += red[(g+s)*8+h];
        __syncthreads();
    }
    if (t < 8) {
        size_t o = ((size_t)(lc*64 + b)*8 + t)*2;
        Fms[o] = s_m[t]; Fms[o+1] = red[t];
    }
    // --- PV, depth-3 prefetch ring ---
    const int par = t >> 7, c = t & 127;
    float4 acc[8] = {};
    const size_t vstride = (size_t)2*64*512;
    const float* vp = vals + ((size_t)(l0 + par)*64 + b)*512 + c*4;
    float4 v0, v1, v2;
    if (par < nl)     v0 = CF4(vp);
    if (par + 2 < nl) v1 = CF4(vp + vstride);
    if (par + 4 < nl) v2 = CF4(vp + 2*vstride);
    for (int il = par; il < nl; il += 2) {
        float4 pa = CF4(&s_sc[il*8]);
        float4 pb = CF4(&s_sc[il*8 + 4]);
        acc[0].x += pa.x*v0.x; acc[0].y += pa.x*v0.y; acc[0].z += pa.x*v0.z; acc[0].w += pa.x*v0.w;
        acc[1].x += pa.y*v0.x; acc[1].y += pa.y*v0.y; acc[1].z += pa.y*v0.z; acc[1].w += pa.y*v0.w;
        acc[2].x += pa.z*v0.x; acc[2].y += pa.z*v0.y; acc[2].z += pa.z*v0.z; acc[2].w += pa.z*v0.w;
        acc[3].x += pa.w*v0.x; acc[3].y += pa.w*v0.y; acc[3].z += pa.w*v0.z; acc[3].w += pa.w*v0.w;
        acc[4].x += pb.x*v0.x; acc[4].y += pb.x*v0.y; acc[4].z += pb.x*v0.z; acc[4].w += pb.x*v0.w;
        acc[5].x += pb.y*v0.x; acc[5].y += pb.y*v0.y; acc[5].z += pb.y*v0.z; acc[5].w += pb.y*v0.w;
        acc[6].x += pb.z*v0.x; acc[6].y += pb.z*v0.y; acc[6].z += pb.z*v0.z; acc[6].w += pb.z*v0.w;
        acc[7].x += pb.w*v0.x; acc[7].y += pb.w*v0.y; acc[7].z += pb.w*v0.z; acc[7].w += pb.w*v0.w;
        v0 = v1; v1 = v2;
        if (il + 6 < nl) v2 = CF4(vp + 3*vstride);
        vp += vstride;
    }
    __syncthreads();
    if (par == 1) {
        #pragma unroll
        for (int hh = 0; hh < 8; ++hh)
            F4(&s_q[(c*8 + hh)*4]) = acc[hh];
    }
    __syncthreads();
    if (par == 0) {
        #pragma unroll
        for (int hh = 0; hh < 8; ++hh) {
            float4 o = CF4(&s_q[(c*8 + hh)*4]);
            o.x += acc[hh].x; o.y += acc[hh].y; o.z += acc[hh].z; o.w += acc[hh].w;
            F4(&facc_out[hh*512 + c*4]) = o;
        }
    }
}

// ============ k_comb: flash combine over live chunks -> res[64][4096] ============
__global__ __launch_bounds__(256) void k_comb(
    const float* __restrict__ Facc, const float* __restrict__ Fms,
    const int* __restrict__ step, float* __restrict__ res)
{
    __shared__ float wgt[MAXC*8];
    __shared__ float s_inv[8];
    const int b = blockIdx.x, t = threadIdx.x;
    const int nc = (step[b] + ROWS - 1) / ROWS;     // live chunks, >= 1
    if (t < 8) {
        float M = -1e30f;
        for (int i = 0; i < nc; ++i)
            M = fmaxf(M, Fms[((size_t)(i*64 + b)*8 + t)*2]);
        float D = 0.f;
        for (int i = 0; i < nc; ++i) {
            size_t o = ((size_t)(i*64 + b)*8 + t)*2;
            float e = __expf(Fms[o] - M);
            wgt[i*8 + t] = e;
            D += e * Fms[o+1];
        }
        s_inv[t] = 1.f / D;
    }
    __syncthreads();
    #pragma unroll
    for (int j = 0; j < 4; ++j) {
        int f = t + j*256;
        int h = f >> 7;
        float4 a = {0.f, 0.f, 0.f, 0.f};
        for (int i = 0; i < nc; ++i) {
            float wi = wgt[i*8 + h];
            float4 v = CF4(&Facc[((size_t)(i*64) + b)*4096 + f*4]);
            a.x += wi*v.x; a.y += wi*v.y; a.z += wi*v.z; a.w += wi*v.w;
        }
        float inv = s_inv[h];
        a.x *= inv; a.y *= inv; a.z *= inv; a.w *= inv;
        F4(&res[(size_t)b*4096 + f*4]) = a;
    }
}

// ============ tail GEMMs ============
__global__ __launch_bounds__(256) void k_agg(
    const float* __restrict__ res, const float* __restrict__ Wagg,
    float* __restrict__ P5)
{
    const int nt = blockIdx.x, ks = blockIdx.y;     // 8 x 32
    gemm_core(res, nullptr, nullptr, 1, 4096, 128, ks*128,
              Wagg, 512, nt*64, nullptr, P5 + (size_t)ks*64*512, 512);
}

__global__ __launch_bounds__(256) void k_rkv1(
    const float* __restrict__ P5, const float* __restrict__ bagg,
    const float* __restrict__ Wrk1, const float* __restrict__ Wrv1,
    float* __restrict__ P6)
{
    const int nt = blockIdx.x, ks = blockIdx.y, z = blockIdx.z;  // 8 x 4 x 2
    gemm_core(P5, bagg, nullptr, 32, 512, 128, ks*128,
              z ? Wrv1 : Wrk1, 512, nt*64,
              nullptr, P6 + (size_t)(z*4 + ks)*64*512, 512);
}

__global__ __launch_bounds__(256) void k_rkv2(
    const float* __restrict__ P6,
    const float* __restrict__ brk1, const float* __restrict__ brv1,
    const float* __restrict__ Wrk2, const float* __restrict__ Wrv2,
    const float* __restrict__ brk2, const float* __restrict__ brv2,
    float* __restrict__ out)
{
    const int nt = blockIdx.x, z = blockIdx.z;      // 8 x 1 x 2
    gemm_core(P6 + (size_t)z*4*64*512, z ? brv1 : brk1, nullptr, 4, 512, 512, 0,
              z ? Wrv2 : Wrk2, 512, nt*64,
              z ? brv2 : brk2, out + (size_t)z*64*512, 512);
}

// ============ launch ============
extern "C" void kernel_launch(void* const* d_in, const int* in_sizes, int n_in,
                              void* d_out, int out_size, void* d_ws, size_t ws_size,
                              hipStream_t stream) {
    const float* state   = (const float*)d_in[0];
    const float* til     = (const float*)d_in[1];
    const float* keys    = (const float*)d_in[2];
    const float* vals    = (const float*)d_in[3];
    const float* rpe     = (const float*)d_in[4];
    const int*   step    = (const int*)d_in[5];
    const float* W_state = (const float*)d_in[6];
    const float* b_state = (const float*)d_in[7];
    const float* Wcq1 = (const float*)d_in[8];
    const float* bcq1 = (const float*)d_in[9];
    const float* Wcq2 = (const float*)d_in[10];
    const float* bcq2 = (const float*)d_in[11];
    const float* Wq   = (const float*)d_in[12];
    const float* bq   = (const float*)d_in[13];
    const float* Wagg = (const float*)d_in[14];
    const float* bagg = (const float*)d_in[15];
    const float* Wrk1 = (const float*)d_in[16];
    const float* brk1 = (const float*)d_in[17];
    const float* Wrk2 = (const float*)d_in[18];
    const float* brk2 = (const float*)d_in[19];
    const float* Wrv1 = (const float*)d_in[20];
    const float* brv1 = (const float*)d_in[21];
    const float* Wrv2 = (const float*)d_in[22];
    const float* brv2 = (const float*)d_in[23];
    float* out = (float*)d_out;
    float* ws  = (float*)d_ws;

    float* P1   = ws;              // [8][64][256]   131072  dead after k_q2
    float* P2   = ws + 131072;     // [8][64][512]   262144  dead after k_q3
    float* P3   = ws + 393216;     // [8][64][512]   262144  dead after k_qh
    float* P4   = ws + 655360;     // [4][64][4096]  1048576 dead after k_qsum
    float* qh   = ws + 1703936;    // [64][4096]     262144
    float* Facc = ws + 1966080;    // [32][64][4096] 8388608 (live chunks only)
    float* Fms  = ws + 10354688;   // 32*64*8*2      32768
    float* res  = ws + 10387456;   // [64][4096]     262144
    float* P5   = ws;              // [32][64][512]  1048576 (reuses P1..P4)
    float* P6   = ws + 1048576;    // [2][4][64][512] 262144 (reuses P4 tail)

    k_q1  <<<dim3(4,8),   256, 0, stream>>>(state, W_state, P1);
    k_q2  <<<dim3(8,8),   256, 0, stream>>>(P1, b_state, til, Wcq1, P2);
    k_q3  <<<dim3(8,8),   256, 0, stream>>>(P2, bcq1, Wcq2, P3);
    k_qh  <<<dim3(64,4),  256, 0, stream>>>(P3, bcq2, Wq, P4);
    k_qsum<<<64, 256, 0, stream>>>(P4, bq, qh);
    k_fa  <<<dim3(MAXC,64), 256, 0, stream>>>(keys, rpe, qh, vals, step, Facc, Fms);
    k_comb<<<64, 256, 0, stream>>>(Facc, Fms, step, res);
    k_agg <<<dim3(8,32),  256, 0, stream>>>(res, Wagg, P5);
    k_rkv1<<<dim3(8,4,2), 256, 0, stream>>>(P5, bagg, Wrk1, Wrv1, P6);
    k_rkv2<<<dim3(8,1,2), 256, 0, stream>>>(P6, brk1, brv1, Wrk2, Wrv2,
                                            brk2, brv2, out);
}

// Round 12
// 159.772 us; speedup vs baseline: 1.1379x; 1.1379x over previous
//
#include <hip/hip_runtime.h>
#include <math.h>

#define F4(p)  (*reinterpret_cast<float4*>(p))
#define CF4(p) (*reinterpret_cast<const float4*>(p))

#define NCHUNK 16

// ============ shared 64x64-tile GEMM core (256 threads) ============
__device__ __forceinline__ void gemm_core(
    const float* __restrict__ Asrc, const float* __restrict__ inbias,
    const float* __restrict__ til,
    int NS, int srcld, int kc, int k0,
    const float* __restrict__ W, int ldw, int n0,
    const float* __restrict__ obias, float* __restrict__ Pout, int ldo)
{
    __shared__ float As[16*64], Ws[16*64];
    const int t = threadIdx.x;
    const int tx = t & 15, ty = t >> 4;
    const int row = t >> 2, kq = (t & 3) * 4;
    const int wrow = t >> 4, wcol = (t & 15) * 4;
    float acc[4][4] = {};
    for (int kk = 0; kk < kc; kk += 16) {
        const int kg = k0 + kk + kq;
        float4 av;
        if (til && kg >= 256) {
            av = CF4(&til[row*256 + (kg - 256)]);
        } else {
            av = {0.f, 0.f, 0.f, 0.f};
            if (inbias) av = CF4(&inbias[kg]);
            for (int s = 0; s < NS; ++s) {
                float4 v = CF4(&Asrc[(size_t)(s*64 + row)*srcld + kg]);
                av.x += v.x; av.y += v.y; av.z += v.z; av.w += v.w;
            }
        }
        As[(kq+0)*64+row] = av.x; As[(kq+1)*64+row] = av.y;
        As[(kq+2)*64+row] = av.z; As[(kq+3)*64+row] = av.w;
        F4(&Ws[wrow*64 + wcol]) = CF4(&W[(size_t)(k0 + kk + wrow)*ldw + n0 + wcol]);
        __syncthreads();
        #pragma unroll
        for (int k = 0; k < 16; ++k) {
            float4 a4 = CF4(&As[k*64 + ty*4]);
            float4 w4 = CF4(&Ws[k*64 + tx*4]);
            float a[4] = {a4.x, a4.y, a4.z, a4.w};
            float w[4] = {w4.x, w4.y, w4.z, w4.w};
            #pragma unroll
            for (int i = 0; i < 4; ++i)
                #pragma unroll
                for (int j = 0; j < 4; ++j)
                    acc[i][j] += a[i] * w[j];
        }
        __syncthreads();
    }
    #pragma unroll
    for (int i = 0; i < 4; ++i) {
        float4 o = {acc[i][0], acc[i][1], acc[i][2], acc[i][3]};
        if (obias) {
            float4 ob = CF4(&obias[n0 + tx*4]);
            o.x += ob.x; o.y += ob.y; o.z += ob.z; o.w += ob.w;
        }
        F4(&Pout[(size_t)(ty*4 + i)*ldo + n0 + tx*4]) = o;
    }
}

// ============ q-chain as split-K GEMMs ============
__global__ __launch_bounds__(256) void k_q1(
    const float* __restrict__ state, const float* __restrict__ W_state,
    float* __restrict__ P1)
{
    const int nt = blockIdx.x, ks = blockIdx.y;     // 4 x 8
    gemm_core(state, nullptr, nullptr, 1, 512, 64, ks*64,
              W_state, 256, nt*64, nullptr, P1 + (size_t)ks*64*256, 256);
}

__global__ __launch_bounds__(256) void k_q2(
    const float* __restrict__ P1, const float* __restrict__ b_state,
    const float* __restrict__ til, const float* __restrict__ Wcq1,
    float* __restrict__ P2)
{
    const int nt = blockIdx.x, ks = blockIdx.y;     // 8 x 8
    gemm_core(P1, b_state, til, 8, 256, 64, ks*64,
              Wcq1, 512, nt*64, nullptr, P2 + (size_t)ks*64*512, 512);
}

__global__ __launch_bounds__(256) void k_q3(
    const float* __restrict__ P2, const float* __restrict__ bcq1,
    const float* __restrict__ Wcq2, float* __restrict__ P3)
{
    const int nt = blockIdx.x, ks = blockIdx.y;     // 8 x 8
    gemm_core(P2, bcq1, nullptr, 8, 512, 64, ks*64,
              Wcq2, 512, nt*64, nullptr, P3 + (size_t)ks*64*512, 512);
}

__global__ __launch_bounds__(256) void k_qh(
    const float* __restrict__ P3, const float* __restrict__ bcq2,
    const float* __restrict__ Wq, float* __restrict__ P4)
{
    const int nt = blockIdx.x, ks = blockIdx.y;     // 64 x 4
    gemm_core(P3, bcq2, nullptr, 8, 512, 128, ks*128,
              Wq, 4096, nt*64, nullptr, P4 + (size_t)ks*64*4096, 4096);
}

// ============ k_qsum: qh[b] = bq + sum4 P4 ============
__global__ __launch_bounds__(256) void k_qsum(
    const float* __restrict__ P4, const float* __restrict__ bq,
    float* __restrict__ qh)
{
    const int b = blockIdx.x, t = threadIdx.x;
    #pragma unroll
    for (int j = 0; j < 4; ++j) {
        int f = t + j*256;
        float4 v = CF4(&bq[f*4]);
        #pragma unroll
        for (int s = 0; s < 4; ++s) {
            float4 u = CF4(&P4[(size_t)(s*64 + b)*4096 + f*4]);
            v.x += u.x; v.y += u.y; v.z += u.z; v.w += u.w;
        }
        F4(&qh[(size_t)b*4096 + f*4]) = v;
    }
}

// ============ k_fa: flash attention, dual-stream prefetch rings ============
__global__ __launch_bounds__(256, 4) void k_fa(
    const float* __restrict__ keys, const float* __restrict__ rpe,
    const float* __restrict__ qh, const float* __restrict__ vals,
    const int* __restrict__ step,
    float* __restrict__ Facc, float* __restrict__ Fms)
{
    __shared__ float s_cmb[4096];     // 16KB: final parity combine scratch
    __shared__ float s_sc[64*8];
    __shared__ float s_rpe[64];
    __shared__ float red[256];
    __shared__ float s_m[8];
    const int b = blockIdx.y, lc = blockIdx.x;
    const int sb = step[b];
    const int l0 = (lc * sb) / NCHUNK;
    const int l1 = ((lc + 1) * sb) / NCHUNK;
    const int nl = l1 - l0;                       // <= 64
    const int t = threadIdx.x;
    float* facc_out = Facc + ((size_t)(lc*64) + b)*4096;
    if (nl <= 0) {
        float4 z = {0.f, 0.f, 0.f, 0.f};
        for (int i = t; i < 1024; i += 256) F4(&facc_out[i*4]) = z;
        if (t < 8) {
            size_t o = ((size_t)(lc*64 + b)*8 + t)*2;
            Fms[o] = -1e30f; Fms[o+1] = 0.f;
        }
        return;
    }
    const float inv_sqrtK = 0.04419417382415922f;
    if (t < nl) s_rpe[t] = rpe[(l0 + t)*64 + b] * inv_sqrtK;
    __syncthreads();

    const int lane = t & 63, w = t >> 6;
    // q fragments straight from global (L2) -> registers
    float qr[8][8];
    {
        const float* qb = qh + (size_t)b*4096 + lane*8;
        #pragma unroll
        for (int h = 0; h < 8; ++h) {
            float4 x = CF4(&qb[h*512]);
            float4 y = CF4(&qb[h*512 + 4]);
            qr[h][0]=x.x; qr[h][1]=x.y; qr[h][2]=x.z; qr[h][3]=x.w;
            qr[h][4]=y.x; qr[h][5]=y.y; qr[h][6]=y.z; qr[h][7]=y.w;
        }
    }
    const bool p0 = lane & 1, p1 = lane & 2, p2 = lane & 4;
    const size_t RS = (size_t)64*512;             // one l-row stride (floats)

    auto score_row = [&](float4 kx, float4 ky, int r) {
        float kv[8] = {kx.x,kx.y,kx.z,kx.w, ky.x,ky.y,ky.z,ky.w};
        float pr[8] = {};
        #pragma unroll
        for (int h = 0; h < 8; ++h)
            #pragma unroll
            for (int j = 0; j < 8; ++j)
                pr[h] += kv[j] * qr[h][j];
        float w4[4], x2[2], y;
        #pragma unroll
        for (int q = 0; q < 4; ++q) {
            float keep = p0 ? pr[2*q+1] : pr[2*q];
            float send = p0 ? pr[2*q]   : pr[2*q+1];
            w4[q] = keep + __shfl_xor(send, 1);
        }
        #pragma unroll
        for (int q = 0; q < 2; ++q) {
            float keep = p1 ? w4[2*q+1] : w4[2*q];
            float send = p1 ? w4[2*q]   : w4[2*q+1];
            x2[q] = keep + __shfl_xor(send, 2);
        }
        {
            float keep = p2 ? x2[1] : x2[0];
            float send = p2 ? x2[0] : x2[1];
            y = keep + __shfl_xor(send, 4);
        }
        y += __shfl_xor(y, 8);
        y += __shfl_xor(y, 16);
        y += __shfl_xor(y, 32);
        if (lane < 8) s_sc[r*8 + lane] = y * s_rpe[r];
    };

    // --- scores: two streams per wave (rows w+8j and w+4+8j), depth-2 each ---
    {
        const float* kpA = keys + ((size_t)(l0 + w)*64 + b)*512 + lane*8;
        const float* kpB = kpA + 4*RS;
        float4 A0x, A0y, A1x, A1y, B0x, B0y, B1x, B1y;
        if (w < nl)      { A0x = CF4(kpA);        A0y = CF4(kpA + 4); }
        if (w + 4 < nl)  { B0x = CF4(kpB);        B0y = CF4(kpB + 4); }
        if (w + 8 < nl)  { A1x = CF4(kpA + 8*RS); A1y = CF4(kpA + 8*RS + 4); }
        if (w + 12 < nl) { B1x = CF4(kpB + 8*RS); B1y = CF4(kpB + 8*RS + 4); }
        for (int il = w; il < nl; il += 8) {
            score_row(A0x, A0y, il);
            A0x = A1x; A0y = A1y;
            if (il + 16 < nl) { A1x = CF4(kpA + 16*RS); A1y = CF4(kpA + 16*RS + 4); }
            kpA += 8*RS;
            if (il + 4 < nl) {
                score_row(B0x, B0y, il + 4);
                B0x = B1x; B0y = B1y;
                if (il + 20 < nl) { B1x = CF4(kpB + 16*RS); B1y = CF4(kpB + 16*RS + 4); }
                kpB += 8*RS;
            }
        }
    }
    __syncthreads();
    // --- local softmax stats ---
    const int h = t & 7, g = t >> 3;
    float m = -1e30f;
    for (int l = g; l < nl; l += 32) m = fmaxf(m, s_sc[l*8 + h]);
    red[g*8 + h] = m;
    __syncthreads();
    #pragma unroll
    for (int s = 16; s; s >>= 1) {
        if (g < s) red[g*8+h] = fmaxf(red[g*8+h], red[(g+s)*8+h]);
        __syncthreads();
    }
    if (t < 8) s_m[t] = red[t];
    __syncthreads();
    float mh = s_m[h], s_acc = 0.f;
    for (int l = g; l < nl; l += 32) {
        float e = __expf(s_sc[l*8 + h] - mh);
        s_sc[l*8 + h] = e;
        s_acc += e;
    }
    red[g*8 + h] = s_acc;
    __syncthreads();
    #pragma unroll
    for (int s = 16; s; s >>= 1) {
        if (g < s) red[g*8+h] += red[(g+s)*8+h];
        __syncthreads();
    }
    if (t < 8) {
        size_t o = ((size_t)(lc*64 + b)*8 + t)*2;
        Fms[o] = s_m[t]; Fms[o+1] = red[t];
    }
    // --- PV: two streams per half-block (rows par+4j and par+2+4j), depth-2 ---
    const int par = t >> 7, c = t & 127;
    float4 acc[8] = {};
    auto pv_row = [&](float4 v, int row) {
        float4 pa = CF4(&s_sc[row*8]);
        float4 pb = CF4(&s_sc[row*8 + 4]);
        acc[0].x += pa.x*v.x; acc[0].y += pa.x*v.y; acc[0].z += pa.x*v.z; acc[0].w += pa.x*v.w;
        acc[1].x += pa.y*v.x; acc[1].y += pa.y*v.y; acc[1].z += pa.y*v.z; acc[1].w += pa.y*v.w;
        acc[2].x += pa.z*v.x; acc[2].y += pa.z*v.y; acc[2].z += pa.z*v.z; acc[2].w += pa.z*v.w;
        acc[3].x += pa.w*v.x; acc[3].y += pa.w*v.y; acc[3].z += pa.w*v.z; acc[3].w += pa.w*v.w;
        acc[4].x += pb.x*v.x; acc[4].y += pb.x*v.y; acc[4].z += pb.x*v.z; acc[4].w += pb.x*v.w;
        acc[5].x += pb.y*v.x; acc[5].y += pb.y*v.y; acc[5].z += pb.y*v.z; acc[5].w += pb.y*v.w;
        acc[6].x += pb.z*v.x; acc[6].y += pb.z*v.y; acc[6].z += pb.z*v.z; acc[6].w += pb.z*v.w;
        acc[7].x += pb.w*v.x; acc[7].y += pb.w*v.y; acc[7].z += pb.w*v.z; acc[7].w += pb.w*v.w;
    };
    {
        const float* vpA = vals + ((size_t)(l0 + par)*64 + b)*512 + c*4;
        const float* vpB = vpA + 2*RS;
        float4 VA0, VA1, VB0, VB1;
        if (par < nl)     VA0 = CF4(vpA);
        if (par + 2 < nl) VB0 = CF4(vpB);
        if (par + 4 < nl) VA1 = CF4(vpA + 4*RS);
        if (par + 6 < nl) VB1 = CF4(vpB + 4*RS);
        for (int il = par; il < nl; il += 4) {
            pv_row(VA0, il);
            VA0 = VA1;
            if (il + 8 < nl) VA1 = CF4(vpA + 8*RS);
            vpA += 4*RS;
            if (il + 2 < nl) {
                pv_row(VB0, il + 2);
                VB0 = VB1;
                if (il + 10 < nl) VB1 = CF4(vpB + 8*RS);
                vpB += 4*RS;
            }
        }
    }
    __syncthreads();
    if (par == 1) {
        #pragma unroll
        for (int hh = 0; hh < 8; ++hh)
            F4(&s_cmb[(c*8 + hh)*4]) = acc[hh];
    }
    __syncthreads();
    if (par == 0) {
        #pragma unroll
        for (int hh = 0; hh < 8; ++hh) {
            float4 o = CF4(&s_cmb[(c*8 + hh)*4]);
            o.x += acc[hh].x; o.y += acc[hh].y; o.z += acc[hh].z; o.w += acc[hh].w;
            F4(&facc_out[hh*512 + c*4]) = o;
        }
    }
}

// ============ k_comb: flash combine -> res[64][4096] ============
__global__ __launch_bounds__(256) void k_comb(
    const float* __restrict__ Facc, const float* __restrict__ Fms,
    float* __restrict__ res)
{
    __shared__ float wgt[NCHUNK*8];
    const int b = blockIdx.x, t = threadIdx.x;
    if (t < 8) {
        float mm[NCHUNK], ss[NCHUNK], e[NCHUNK];
        float M = -1e30f;
        #pragma unroll
        for (int i = 0; i < NCHUNK; ++i) {
            size_t o = ((size_t)(i*64 + b)*8 + t)*2;
            mm[i] = Fms[o]; ss[i] = Fms[o+1];
            M = fmaxf(M, mm[i]);
        }
        float D = 0.f;
        #pragma unroll
        for (int i = 0; i < NCHUNK; ++i) { e[i] = __expf(mm[i] - M); D += e[i]*ss[i]; }
        float invD = 1.f / D;
        #pragma unroll
        for (int i = 0; i < NCHUNK; ++i) wgt[i*8 + t] = e[i] * invD;
    }
    __syncthreads();
    #pragma unroll
    for (int j = 0; j < 4; ++j) {
        int f = t + j*256;
        int h = f >> 7;
        float4 a = {0.f, 0.f, 0.f, 0.f};
        #pragma unroll
        for (int i = 0; i < NCHUNK; ++i) {
            float wi = wgt[i*8 + h];
            float4 v = CF4(&Facc[((size_t)(i*64) + b)*4096 + f*4]);
            a.x += wi*v.x; a.y += wi*v.y; a.z += wi*v.z; a.w += wi*v.w;
        }
        F4(&res[(size_t)b*4096 + f*4]) = a;
    }
}

// ============ tail GEMMs ============
__global__ __launch_bounds__(256) void k_agg(
    const float* __restrict__ res, const float* __restrict__ Wagg,
    float* __restrict__ P5)
{
    const int nt = blockIdx.x, ks = blockIdx.y;     // 8 x 32
    gemm_core(res, nullptr, nullptr, 1, 4096, 128, ks*128,
              Wagg, 512, nt*64, nullptr, P5 + (size_t)ks*64*512, 512);
}

__global__ __launch_bounds__(256) void k_rkv1(
    const float* __restrict__ P5, const float* __restrict__ bagg,
    const float* __restrict__ Wrk1, const float* __restrict__ Wrv1,
    float* __restrict__ P6)
{
    const int nt = blockIdx.x, ks = blockIdx.y, z = blockIdx.z;  // 8 x 4 x 2
    gemm_core(P5, bagg, nullptr, 32, 512, 128, ks*128,
              z ? Wrv1 : Wrk1, 512, nt*64,
              nullptr, P6 + (size_t)(z*4 + ks)*64*512, 512);
}

__global__ __launch_bounds__(256) void k_rkv2(
    const float* __restrict__ P6,
    const float* __restrict__ brk1, const float* __restrict__ brv1,
    const float* __restrict__ Wrk2, const float* __restrict__ Wrv2,
    const float* __restrict__ brk2, const float* __restrict__ brv2,
    float* __restrict__ out)
{
    const int nt = blockIdx.x, z = blockIdx.z;      // 8 x 1 x 2
    gemm_core(P6 + (size_t)z*4*64*512, z ? brv1 : brk1, nullptr, 4, 512, 512, 0,
              z ? Wrv2 : Wrk2, 512, nt*64,
              z ? brv2 : brk2, out + (size_t)z*64*512, 512);
}

// ============ launch ============
extern "C" void kernel_launch(void* const* d_in, const int* in_sizes, int n_in,
                              void* d_out, int out_size, void* d_ws, size_t ws_size,
                              hipStream_t stream) {
    const float* state   = (const float*)d_in[0];
    const float* til     = (const float*)d_in[1];
    const float* keys    = (const float*)d_in[2];
    const float* vals    = (const float*)d_in[3];
    const float* rpe     = (const float*)d_in[4];
    const int*   step    = (const int*)d_in[5];
    const float* W_state = (const float*)d_in[6];
    const float* b_state = (const float*)d_in[7];
    const float* Wcq1 = (const float*)d_in[8];
    const float* bcq1 = (const float*)d_in[9];
    const float* Wcq2 = (const float*)d_in[10];
    const float* bcq2 = (const float*)d_in[11];
    const float* Wq   = (const float*)d_in[12];
    const float* bq   = (const float*)d_in[13];
    const float* Wagg = (const float*)d_in[14];
    const float* bagg = (const float*)d_in[15];
    const float* Wrk1 = (const float*)d_in[16];
    const float* brk1 = (const float*)d_in[17];
    const float* Wrk2 = (const float*)d_in[18];
    const float* brk2 = (const float*)d_in[19];
    const float* Wrv1 = (const float*)d_in[20];
    const float* brv1 = (const float*)d_in[21];
    const float* Wrv2 = (const float*)d_in[22];
    const float* brv2 = (const float*)d_in[23];
    float* out = (float*)d_out;
    float* ws  = (float*)d_ws;

    float* P1   = ws;              // [8][64][256]   131072  dead after k_q2
    float* P2   = ws + 131072;     // [8][64][512]   262144  dead after k_q3
    float* P3   = ws + 393216;     // [8][64][512]   262144  dead after k_qh
    float* P4   = ws + 655360;     // [4][64][4096]  1048576 dead after k_qsum
    float* qh   = ws + 1703936;    // [64][4096]     262144
    float* Facc = ws + 1966080;    // [16][64][4096] 4194304
    float* Fms  = ws + 6160384;    // 16*64*8*2      16384
    float* res  = ws + 6176768;    // [64][4096]     262144
    float* P5   = ws;              // [32][64][512]  1048576 (reuses P1..P4)
    float* P6   = ws + 1048576;    // [2][4][64][512] 262144 (reuses P4 tail)

    k_q1  <<<dim3(4,8),   256, 0, stream>>>(state, W_state, P1);
    k_q2  <<<dim3(8,8),   256, 0, stream>>>(P1, b_state, til, Wcq1, P2);
    k_q3  <<<dim3(8,8),   256, 0, stream>>>(P2, bcq1, Wcq2, P3);
    k_qh  <<<dim3(64,4),  256, 0, stream>>>(P3, bcq2, Wq, P4);
    k_qsum<<<64, 256, 0, stream>>>(P4, bq, qh);
    k_fa  <<<dim3(NCHUNK,64), 256, 0, stream>>>(keys, rpe, qh, vals, step, Facc, Fms);
    k_comb<<<64, 256, 0, stream>>>(Facc, Fms, res);
    k_agg <<<dim3(8,32),  256, 0, stream>>>(res, Wagg, P5);
    k_rkv1<<<dim3(8,4,2), 256, 0, stream>>>(P5, bagg, Wrk1, Wrv1, P6);
    k_rkv2<<<dim3(8,1,2), 256, 0, stream>>>(P6, brk1, brv1, Wrk2, Wrv2,
                                            brk2, brv2, out);
}